// Round 1
// baseline (7474.409 us; speedup 1.0000x reference)
//
#include <hip/hip_runtime.h>
#include <cstdint>

// ---------------- problem constants ----------------
#define DIM      300
#define KPAD     320          // DIM padded for GEMM (zeros in 300..319)
#define NITEMS   39999        // all_item rows (embedding_weight[1:])
#define NPAD     40064        // 313 * 128
#define NROWQ    12928        // 12800 sample rows + 64 sess rows + pad, =101*128
#define BATCH    64
#define LSEQ     20
#define SNEG     5
#define NEXP     20
#define MAPPAD   384          // map_dense cols padded, 3*128

#define TGT      140          // candidates to keep before f64 re-rank
#define CAP      512          // candidate buffer (bitonic size)

// output offsets (floats)
#define O_LOSS   0LL
#define O_SCORES 1LL
#define O_SUB    (1LL + 64LL*39999LL)               // 2559937
#define O_COMP   (O_SUB + 64LL*20LL*100LL*300LL)    // 40959937
#define O_SMAP   (O_COMP + 64LL*20LL*100LL*300LL)   // 79359937

// ---------------- small pipeline kernels ----------------

// interfeat = table[inputs] (row 0 zeroed), hs = masked mean over L
__global__ void kA(const float* __restrict__ E, const int* __restrict__ inputs,
                   const int* __restrict__ masks, float* __restrict__ interfeat,
                   float* __restrict__ hs) {
    int b = blockIdx.x, t = threadIdx.x;           // 320 threads
    int cnt = 0;
    for (int l = 0; l < LSEQ; ++l) cnt += masks[b*LSEQ + l];
    if (t < DIM) {
        float acc = 0.f;
        for (int l = 0; l < LSEQ; ++l) {
            int idx = inputs[b*LSEQ + l];
            float v = (idx == 0) ? 0.f : E[(long long)idx*DIM + t];
            interfeat[(b*LSEQ + l)*DIM + t] = v;
            if (masks[b*LSEQ + l]) acc += v;
        }
        hs[b*DIM + t] = acc / (float)cnt;
    }
}

// posw1[l][j] = sum_k pos[l][k] * w1[k][j]
__global__ void kB0(const float* __restrict__ pos, const float* __restrict__ w1,
                    float* __restrict__ posw1) {
    int l = blockIdx.x, j = threadIdx.x;
    if (j >= DIM) return;
    float acc = 0.f;
    for (int k = 0; k < DIM; ++k) acc = fmaf(pos[l*DIM + k], w1[k*DIM + j], acc);
    posw1[l*DIM + j] = acc;
}

// hsg[b][j] = sum_k hs[b][k] * glu2_w[k][j]
__global__ void kB0b(const float* __restrict__ hs, const float* __restrict__ g2,
                     float* __restrict__ hsg) {
    int b = blockIdx.x, j = threadIdx.x;
    if (j >= DIM) return;
    float acc = 0.f;
    for (int k = 0; k < DIM; ++k) acc = fmaf(hs[b*DIM + k], g2[k*DIM + j], acc);
    hsg[b*DIM + j] = acc;
}

// nh1 = tanh(posw1[l] + seq[b,l] @ w1[300:600])
__global__ void kB1(const float* __restrict__ interfeat, const float* __restrict__ w1,
                    const float* __restrict__ posw1, float* __restrict__ nh1) {
    int bl = blockIdx.x;                 // b*20+l
    int l  = bl % LSEQ;
    __shared__ float s[DIM];
    int t = threadIdx.x;
    if (t < DIM) s[t] = interfeat[bl*DIM + t];
    __syncthreads();
    if (t >= DIM) return;
    float acc = posw1[l*DIM + t];
    for (int k = 0; k < DIM; ++k) acc = fmaf(s[k], w1[(DIM + k)*DIM + t], acc);
    nh1[bl*DIM + t] = tanhf(acc);
}

// nh2 = sigmoid(nh1 @ glu1_w + glu1_b + hsg[b]); beta = (nh2 . w2) * mask
__global__ void kB2(const float* __restrict__ nh1, const float* __restrict__ g1w,
                    const float* __restrict__ g1b, const float* __restrict__ hsg,
                    const float* __restrict__ w2, const int* __restrict__ masks,
                    float* __restrict__ betav) {
    int bl = blockIdx.x, b = bl / LSEQ;
    __shared__ float s[DIM];
    __shared__ float wsum[5];
    int t = threadIdx.x;                 // 320
    if (t < DIM) s[t] = nh1[bl*DIM + t];
    __syncthreads();
    float contrib = 0.f;
    if (t < DIM) {
        float acc = g1b[t] + hsg[b*DIM + t];
        for (int k = 0; k < DIM; ++k) acc = fmaf(s[k], g1w[k*DIM + t], acc);
        float v = 1.f / (1.f + expf(-acc));
        contrib = v * w2[t];
    }
    float v = contrib;
    for (int off = 32; off; off >>= 1) v += __shfl_down(v, off);
    if ((t & 63) == 0) wsum[t >> 6] = v;
    __syncthreads();
    if (t == 0) {
        float tot = wsum[0] + wsum[1] + wsum[2] + wsum[3] + wsum[4];
        betav[bl] = tot * (float)masks[bl];
    }
}

// sess = sum_l beta*seq; sess_i = 10*l2norm(sess); also write into qbufT rows 12800+b
__global__ void kB3(const float* __restrict__ interfeat, const float* __restrict__ betav,
                    float* __restrict__ sess_i, float* __restrict__ qbufT) {
    int b = blockIdx.x, t = threadIdx.x; // 320
    float sd = 0.f;
    if (t < DIM)
        for (int l = 0; l < LSEQ; ++l)
            sd = fmaf(betav[b*LSEQ + l], interfeat[(b*LSEQ + l)*DIM + t], sd);
    float ss = (t < DIM) ? sd*sd : 0.f;
    for (int off = 32; off; off >>= 1) ss += __shfl_down(ss, off);
    __shared__ float wsum[5];
    __shared__ float snorm;
    if ((t & 63) == 0) wsum[t >> 6] = ss;
    __syncthreads();
    if (t == 0) {
        float tot = wsum[0] + wsum[1] + wsum[2] + wsum[3] + wsum[4];
        snorm = 10.f / fmaxf(sqrtf(tot), 1e-12f);
    }
    __syncthreads();
    if (t < DIM) {
        float v = sd * snorm;
        sess_i[b*DIM + t] = v;
        qbufT[(long long)t*NROWQ + 12800 + b] = v;
    }
}

// gather+transpose 32 rows of E into K-major dstT[k][col]
__global__ void fill_T(const float* __restrict__ E, const int* __restrict__ idx,
                       int idx_off1, float* __restrict__ dstT, int dst_stride,
                       int col0_base, int idx_shift, int nrows) {
    __shared__ float lds[32*301];
    int c0 = col0_base + blockIdx.x*32;
    int t = threadIdx.x;                 // 256
    for (int i = t; i < 32*75; i += 256) {
        int r = i / 75, f4i = i % 75;
        int grow = c0 + r;
        float4 v = make_float4(0.f, 0.f, 0.f, 0.f);
        if (grow < nrows) {
            int erow = idx ? idx[grow - idx_shift] : (grow + idx_off1);
            v = *(const float4*)(E + (long long)erow*DIM + f4i*4);
        }
        lds[r*301 + f4i*4 + 0] = v.x;
        lds[r*301 + f4i*4 + 1] = v.y;
        lds[r*301 + f4i*4 + 2] = v.z;
        lds[r*301 + f4i*4 + 3] = v.w;
    }
    __syncthreads();
    for (int i = t; i < DIM*32; i += 256) {
        int k = i >> 5, col = i & 31;
        dstT[(long long)k*dst_stride + c0 + col] = lds[col*301 + k];
    }
}

__global__ void mapfill(const float* __restrict__ m, float* __restrict__ mp) {
    int k = blockIdx.x, j = threadIdx.x;
    if (j < DIM) mp[k*MAPPAD + j] = m[k*DIM + j];
}

__global__ void inv_norm_k(const float* __restrict__ E, float* __restrict__ invn) {
    int n = blockIdx.x;                  // 0..NITEMS-1
    const float* row = E + (long long)(n + 1)*DIM;
    int t = threadIdx.x;                 // 64
    float ss = 0.f;
    for (int k = t; k < DIM; k += 64) { float v = row[k]; ss += v*v; }
    for (int off = 32; off; off >>= 1) ss += __shfl_down(ss, off);
    if (t == 0) invn[n] = 1.f / fmaxf(sqrtf(ss), 1e-12f);
}

// ---------------- f32 tiled GEMM: C[r][n] = sum_k At[k][r]*Bt[k][n] ----------------
__launch_bounds__(256)
__global__ void gemm_tn(const float* __restrict__ At, int a_stride, int a_row0,
                        const float* __restrict__ Bt, int b_stride,
                        float* __restrict__ C, long long c_stride, int c_row0) {
    __shared__ float As[64*128];
    __shared__ float Bs[64*128];
    const int t  = threadIdx.x;
    const int tx = t & 15, ty = t >> 4;
    const int n0 = blockIdx.x * 128;
    const int r0 = a_row0 + blockIdx.y * 128;
    float acc[8][8];
#pragma unroll
    for (int i = 0; i < 8; ++i)
#pragma unroll
        for (int j = 0; j < 8; ++j) acc[i][j] = 0.f;

    for (int kt = 0; kt < 5; ++kt) {     // K = 320 = 5 * 64
        const int k0 = kt * 64;
#pragma unroll
        for (int i = 0; i < 8; ++i) {    // 64x32 float4 per slab, 8 per thread
            int idx = t + 256*i;
            int k = idx >> 5, c4 = idx & 31;
            float4 va = *(const float4*)(At + (long long)(k0 + k)*a_stride + r0 + c4*4);
            *(float4*)(As + k*128 + c4*4) = va;
            float4 vb = *(const float4*)(Bt + (long long)(k0 + k)*b_stride + n0 + c4*4);
            *(float4*)(Bs + k*128 + c4*4) = vb;
        }
        __syncthreads();
#pragma unroll 4
        for (int k = 0; k < 64; ++k) {
            float4 a0 = *(const float4*)(As + k*128 + ty*8);
            float4 a1 = *(const float4*)(As + k*128 + ty*8 + 4);
            float4 b0 = *(const float4*)(Bs + k*128 + tx*8);
            float4 b1 = *(const float4*)(Bs + k*128 + tx*8 + 4);
            float a[8] = {a0.x,a0.y,a0.z,a0.w,a1.x,a1.y,a1.z,a1.w};
            float b[8] = {b0.x,b0.y,b0.z,b0.w,b1.x,b1.y,b1.z,b1.w};
#pragma unroll
            for (int i = 0; i < 8; ++i)
#pragma unroll
                for (int j = 0; j < 8; ++j)
                    acc[i][j] = fmaf(a[i], b[j], acc[i][j]);
        }
        __syncthreads();
    }
    const long long rbase = (long long)(r0 - c_row0);
#pragma unroll
    for (int i = 0; i < 8; ++i) {
        float* dst = C + (rbase + ty*8 + i)*c_stride + n0 + tx*8;
        *(float4*)(dst)     = make_float4(acc[i][0], acc[i][1], acc[i][2], acc[i][3]);
        *(float4*)(dst + 4) = make_float4(acc[i][4], acc[i][5], acc[i][6], acc[i][7]);
    }
}

// ---------------- fused top-K: histogram threshold -> f64 re-rank -> sort ----------------
__launch_bounds__(256)
__global__ void topk_k(const float* __restrict__ sim, int chunk_row0,
                       const float* __restrict__ E, const float* __restrict__ qbufT,
                       int* __restrict__ topk) {
    const int r = chunk_row0 + blockIdx.x;
    const float* row = sim + (long long)blockIdx.x * NPAD;
    const int t = threadIdx.x;           // 256

    __shared__ unsigned hist[256];
    __shared__ unsigned s_T, s_above, s_total, s_cnt;
    __shared__ unsigned ckey_u[CAP];
    __shared__ int      cidx[CAP];
    __shared__ double   cval[CAP];
    __shared__ float    qs[DIM];

    for (int k = t; k < DIM; k += 256) qs[k] = qbufT[(long long)k*NROWQ + r];
    if (t == 0) s_cnt = 0;

    unsigned T = 0, above = 0;
    for (int shift = 24; shift >= 0; shift -= 8) {
        hist[t] = 0;
        __syncthreads();
        unsigned prefmask = (shift == 24) ? 0u : (0xFFFFFFFFu << (shift + 8));
        for (int n = t; n < NITEMS; n += 256) {
            unsigned b = __float_as_uint(row[n]);
            unsigned u = (b & 0x80000000u) ? ~b : (b | 0x80000000u);
            if ((u & prefmask) == (T & prefmask))
                atomicAdd(&hist[(u >> shift) & 0xFFu], 1u);
        }
        __syncthreads();
        if (t == 0) {
            unsigned cum = above, prev = above;
            int bb = 255;
            for (; bb >= 0; --bb) {
                cum += hist[bb];
                if (cum >= TGT) break;
                prev = cum;
            }
            if (bb < 0) bb = 0;
            s_T = T | ((unsigned)bb << shift);
            s_above = prev;
            s_total = cum;
        }
        __syncthreads();
        T = s_T; above = s_above;
        unsigned total = s_total;
        __syncthreads();
        if (total <= CAP) break;
    }

    // collect candidates with key >= T
    for (int n = t; n < NITEMS; n += 256) {
        unsigned b = __float_as_uint(row[n]);
        unsigned u = (b & 0x80000000u) ? ~b : (b | 0x80000000u);
        if (u >= T) {
            unsigned p = atomicAdd(&s_cnt, 1u);
            if (p < CAP) { ckey_u[p] = u; cidx[p] = n; }
        }
    }
    __syncthreads();
    int cnt = (int)min(s_cnt, (unsigned)CAP);

    // exact f64 re-rank of candidates
    for (int c = t; c < CAP; c += 256) {
        if (c < cnt) {
            int n = cidx[c];
            const float* irow = E + (long long)(n + 1)*DIM;
            double acc = 0.0;
            for (int k = 0; k < DIM; ++k) acc = fma((double)qs[k], (double)irow[k], acc);
            cval[c] = acc;
        } else {
            cval[c] = -1e300;
            cidx[c] = 0x7FFFFFFF;
        }
    }
    __syncthreads();

    // bitonic sort 512, descending by (value, then index ascending)
    for (int k = 2; k <= CAP; k <<= 1) {
        for (int j = k >> 1; j > 0; j >>= 1) {
            int i = ((t & ~(j - 1)) << 1) | (t & (j - 1));
            int p = i | j;
            bool up = (i & k) != 0;
            double v1 = cval[i], v2 = cval[p];
            int    i1 = cidx[i], i2 = cidx[p];
            bool less = (v1 < v2) || (v1 == v2 && i1 > i2);
            if (less != up) { cval[i] = v2; cval[p] = v1; cidx[i] = i2; cidx[p] = i1; }
            __syncthreads();
        }
    }
    if (t < 100) topk[(long long)r*100 + t] = cidx[t];
}

// ---------------- scores epilogue + loss ----------------
__global__ void scores_k(const float* __restrict__ sim, const float* __restrict__ invn,
                         float* __restrict__ out, float* __restrict__ blse) {
    int b = blockIdx.x, t = threadIdx.x;   // 256
    const float* row = sim + (long long)b * NPAD;
    float mx = -1e30f;
    for (int n = t; n < NITEMS; n += 256) {
        float s = row[n] * invn[n];
        out[O_SCORES + (long long)b*NITEMS + n] = s;
        mx = fmaxf(mx, s);
    }
    for (int off = 32; off; off >>= 1) mx = fmaxf(mx, __shfl_down(mx, off));
    __shared__ float wred[4];
    __shared__ float smax;
    if ((t & 63) == 0) wred[t >> 6] = mx;
    __syncthreads();
    if (t == 0) smax = fmaxf(fmaxf(wred[0], wred[1]), fmaxf(wred[2], wred[3]));
    __syncthreads();
    float se = 0.f;
    for (int n = t; n < NITEMS; n += 256) {
        float s = out[O_SCORES + (long long)b*NITEMS + n];
        se += expf(s - smax);
    }
    for (int off = 32; off; off >>= 1) se += __shfl_down(se, off);
    if ((t & 63) == 0) wred[t >> 6] = se;
    __syncthreads();
    if (t == 0) blse[b] = smax + logf(wred[0] + wred[1] + wred[2] + wred[3]);
}

__global__ void loss_k(const float* __restrict__ out_scores, const int* __restrict__ targets,
                       const float* __restrict__ blse, float* __restrict__ out) {
    int t = threadIdx.x;                 // 64
    int lab = targets[t] - 1;
    float lp = out_scores[O_SCORES + (long long)t*NITEMS + lab] - blse[t];
    for (int off = 32; off; off >>= 1) lp += __shfl_down(lp, off);
    if (t == 0) out[0] = -lp / 64.f;
}

// ---------------- final gathers ----------------
__global__ void gather_k(const int* __restrict__ topk, const int* __restrict__ slices,
                         const float* __restrict__ all_mapped, float* __restrict__ out) {
    int r = blockIdx.x;                  // 0..12799
    int t = threadIdx.x;                 // 320
    if (t >= DIM) return;
    int rr = (r < 6400) ? r : r - 6400;
    long long obase = (r < 6400) ? O_SUB : O_COMP;
    int s  = rr % SNEG;
    int bl = rr / SNEG;
    long long outrow = (long long)bl*100 + s*NEXP;
    for (int e = 0; e < NEXP; ++e) {
        int sl = slices[e];
        int idx = topk[(long long)r*100 + sl];
        out[obase + (outrow + e)*DIM + t] = all_mapped[(long long)idx*MAPPAD + t];
    }
}

__global__ void smap_copy(const float* __restrict__ smbuf, float* __restrict__ out) {
    int b = blockIdx.x, t = threadIdx.x;
    if (t < DIM) out[O_SMAP + (long long)b*DIM + t] = smbuf[b*MAPPAD + t];
}

// ---------------- host ----------------
extern "C" void kernel_launch(void* const* d_in, const int* in_sizes, int n_in,
                              void* d_out, int out_size, void* d_ws, size_t ws_size,
                              hipStream_t stream) {
    (void)in_sizes; (void)n_in; (void)out_size;
    const float* E     = (const float*)d_in[0];
    const float* pos   = (const float*)d_in[1];
    const float* w1    = (const float*)d_in[2];
    const float* w2    = (const float*)d_in[3];
    const float* g1w   = (const float*)d_in[4];
    const float* g1b   = (const float*)d_in[5];
    const float* g2w   = (const float*)d_in[6];
    const float* mapd  = (const float*)d_in[7];
    const int* inputs  = (const int*)d_in[8];
    const int* targets = (const int*)d_in[9];
    const int* masks   = (const int*)d_in[10];
    const int* viewed  = (const int*)d_in[11];
    const int* bought  = (const int*)d_in[12];
    const int* slices  = (const int*)d_in[13];
    float* out = (float*)d_out;

    char* w = (char*)d_ws;
    auto alloc = [&](size_t nbytes) {
        char* p = w;
        w += (nbytes + 255) & ~(size_t)255;
        return p;
    };
    float* interfeat  = (float*)alloc(384000 * 4);
    float* nh1        = (float*)alloc(384000 * 4);
    float* hs         = (float*)alloc(19200 * 4);
    float* posw1      = (float*)alloc(6000 * 4);
    float* hsg        = (float*)alloc(19200 * 4);
    float* betav      = (float*)alloc(1280 * 4);
    float* sess_i     = (float*)alloc(19200 * 4);
    float* invn       = (float*)alloc(39999 * 4);
    float* blse       = (float*)alloc(64 * 4);
    int*   topk       = (int*)  alloc((size_t)12800 * 100 * 4);
    float* mapPad     = (float*)alloc((size_t)KPAD * MAPPAD * 4);
    float* all_mapped = (float*)alloc((size_t)NPAD * MAPPAD * 4);
    float* qbufT      = (float*)alloc((size_t)KPAD * NROWQ * 4);
    float* ibufT      = (float*)alloc((size_t)KPAD * NPAD * 4);
    float* simc       = (float*)w;
    size_t rem_floats = (ws_size - (size_t)(w - (char*)d_ws)) / 4;
    int CH = (int)(rem_floats / NPAD);
    CH = (CH / 128) * 128;
    if (CH > 1024) CH = 1024;
    if (CH < 128)  CH = 128;   // minimum viable

    hipMemsetAsync(qbufT, 0, (size_t)KPAD * NROWQ * 4, stream);
    hipMemsetAsync(ibufT, 0, (size_t)KPAD * NPAD * 4, stream);
    hipMemsetAsync(mapPad, 0, (size_t)KPAD * MAPPAD * 4, stream);

    kA  <<<BATCH, 320, 0, stream>>>(E, inputs, masks, interfeat, hs);
    kB0 <<<LSEQ, 320, 0, stream>>>(pos, w1, posw1);
    kB0b<<<BATCH, 320, 0, stream>>>(hs, g2w, hsg);
    kB1 <<<BATCH*LSEQ, 320, 0, stream>>>(interfeat, w1, posw1, nh1);
    kB2 <<<BATCH*LSEQ, 320, 0, stream>>>(nh1, g1w, g1b, hsg, w2, masks, betav);
    kB3 <<<BATCH, 320, 0, stream>>>(interfeat, betav, sess_i, qbufT);

    fill_T<<<NPAD/32, 256, 0, stream>>>(E, nullptr, 1, ibufT, NPAD, 0, 0, NITEMS);
    fill_T<<<200,     256, 0, stream>>>(E, viewed, 0, qbufT, NROWQ, 0,    0,    6400);
    fill_T<<<200,     256, 0, stream>>>(E, bought, 0, qbufT, NROWQ, 6400, 6400, 12800);
    mapfill<<<DIM, 320, 0, stream>>>(mapd, mapPad);
    inv_norm_k<<<NITEMS, 64, 0, stream>>>(E, invn);

    // all_mapped = all_item @ map_dense   (rows padded to NPAD)
    { dim3 g(3, NPAD/128); gemm_tn<<<g, 256, 0, stream>>>(ibufT, NPAD, 0, mapPad, MAPPAD, all_mapped, MAPPAD, 0); }
    // sess_mapped = sess_i @ map_dense  (uses sess rows 12800..12927 of qbufT)
    { dim3 g(3, 1); gemm_tn<<<g, 256, 0, stream>>>(qbufT, NROWQ, 12800, mapPad, MAPPAD, simc, MAPPAD, 12800); }
    smap_copy<<<BATCH, 320, 0, stream>>>(simc, out);

    // big sim GEMM in chunks + fused top-k
    for (int r0 = 0; r0 < 12800; r0 += CH) {
        int ch = (12800 - r0 < CH) ? (12800 - r0) : CH;
        dim3 g(NPAD/128, ch/128);
        gemm_tn<<<g, 256, 0, stream>>>(qbufT, NROWQ, r0, ibufT, NPAD, simc, NPAD, r0);
        topk_k<<<ch, 256, 0, stream>>>(simc, r0, E, qbufT, topk);
    }

    // scores rows (sess) + loss
    { dim3 g(NPAD/128, 1); gemm_tn<<<g, 256, 0, stream>>>(qbufT, NROWQ, 12800, ibufT, NPAD, simc, NPAD, 12800); }
    scores_k<<<BATCH, 256, 0, stream>>>(simc, invn, out, blse);
    loss_k<<<1, 64, 0, stream>>>(out, targets, blse, out);

    gather_k<<<12800, 320, 0, stream>>>(topk, slices, all_mapped, out);
}

// Round 2
// 4656.653 us; speedup vs baseline: 1.6051x; 1.6051x over previous
//
#include <hip/hip_runtime.h>
#include <hip/hip_bf16.h>
#include <cstdint>

typedef unsigned short ushort_t;
typedef __bf16 bf16x8 __attribute__((ext_vector_type(8)));
typedef float  f32x4  __attribute__((ext_vector_type(4)));

// ---------------- problem constants ----------------
#define DIM      300
#define KPAD     320
#define NITEMS   39999
#define NPAD     40064        // 313 * 128
#define NROWQ    12928        // 12800 + 64 sess + pad
#define BATCH    64
#define LSEQ     20
#define SNEG     5
#define NEXP     20
#define MAPPAD   384

#define TGT      140
#define CAP      512

// output offsets (floats)
#define O_LOSS   0LL
#define O_SCORES 1LL
#define O_SUB    (1LL + 64LL*39999LL)
#define O_COMP   (O_SUB + 64LL*20LL*100LL*300LL)
#define O_SMAP   (O_COMP + 64LL*20LL*100LL*300LL)

// ---------------- small pipeline kernels ----------------

__global__ void kA(const float* __restrict__ E, const int* __restrict__ inputs,
                   const int* __restrict__ masks, float* __restrict__ interfeat,
                   float* __restrict__ hs) {
    int b = blockIdx.x, t = threadIdx.x;           // 320
    int cnt = 0;
    for (int l = 0; l < LSEQ; ++l) cnt += masks[b*LSEQ + l];
    if (t < DIM) {
        float acc = 0.f;
        for (int l = 0; l < LSEQ; ++l) {
            int idx = inputs[b*LSEQ + l];
            float v = (idx == 0) ? 0.f : E[(long long)idx*DIM + t];
            interfeat[(b*LSEQ + l)*DIM + t] = v;
            if (masks[b*LSEQ + l]) acc += v;
        }
        hs[b*DIM + t] = acc / (float)cnt;
    }
}

__global__ void kB0(const float* __restrict__ pos, const float* __restrict__ w1,
                    float* __restrict__ posw1) {
    int l = blockIdx.x, j = threadIdx.x;
    if (j >= DIM) return;
    float acc = 0.f;
    for (int k = 0; k < DIM; ++k) acc = fmaf(pos[l*DIM + k], w1[k*DIM + j], acc);
    posw1[l*DIM + j] = acc;
}

__global__ void kB0b(const float* __restrict__ hs, const float* __restrict__ g2,
                     float* __restrict__ hsg) {
    int b = blockIdx.x, j = threadIdx.x;
    if (j >= DIM) return;
    float acc = 0.f;
    for (int k = 0; k < DIM; ++k) acc = fmaf(hs[b*DIM + k], g2[k*DIM + j], acc);
    hsg[b*DIM + j] = acc;
}

__global__ void kB1(const float* __restrict__ interfeat, const float* __restrict__ w1,
                    const float* __restrict__ posw1, float* __restrict__ nh1) {
    int bl = blockIdx.x;
    int l  = bl % LSEQ;
    __shared__ float s[DIM];
    int t = threadIdx.x;
    if (t < DIM) s[t] = interfeat[bl*DIM + t];
    __syncthreads();
    if (t >= DIM) return;
    float acc = posw1[l*DIM + t];
    for (int k = 0; k < DIM; ++k) acc = fmaf(s[k], w1[(DIM + k)*DIM + t], acc);
    nh1[bl*DIM + t] = tanhf(acc);
}

__global__ void kB2(const float* __restrict__ nh1, const float* __restrict__ g1w,
                    const float* __restrict__ g1b, const float* __restrict__ hsg,
                    const float* __restrict__ w2, const int* __restrict__ masks,
                    float* __restrict__ betav) {
    int bl = blockIdx.x, b = bl / LSEQ;
    __shared__ float s[DIM];
    __shared__ float wsum[5];
    int t = threadIdx.x;                 // 320
    if (t < DIM) s[t] = nh1[bl*DIM + t];
    __syncthreads();
    float contrib = 0.f;
    if (t < DIM) {
        float acc = g1b[t] + hsg[b*DIM + t];
        for (int k = 0; k < DIM; ++k) acc = fmaf(s[k], g1w[k*DIM + t], acc);
        float v = 1.f / (1.f + expf(-acc));
        contrib = v * w2[t];
    }
    float v = contrib;
    for (int off = 32; off; off >>= 1) v += __shfl_down(v, off);
    if ((t & 63) == 0) wsum[t >> 6] = v;
    __syncthreads();
    if (t == 0) {
        float tot = wsum[0] + wsum[1] + wsum[2] + wsum[3] + wsum[4];
        betav[bl] = tot * (float)masks[bl];
    }
}

// sess emb -> sess_i (f32) and Aq rows 12800+b (bf16)
__global__ void kB3(const float* __restrict__ interfeat, const float* __restrict__ betav,
                    float* __restrict__ sess_i, ushort_t* __restrict__ Aq) {
    int b = blockIdx.x, t = threadIdx.x; // 320
    float sd = 0.f;
    if (t < DIM)
        for (int l = 0; l < LSEQ; ++l)
            sd = fmaf(betav[b*LSEQ + l], interfeat[(b*LSEQ + l)*DIM + t], sd);
    float ss = (t < DIM) ? sd*sd : 0.f;
    for (int off = 32; off; off >>= 1) ss += __shfl_down(ss, off);
    __shared__ float wsum[5];
    __shared__ float snorm;
    if ((t & 63) == 0) wsum[t >> 6] = ss;
    __syncthreads();
    if (t == 0) {
        float tot = wsum[0] + wsum[1] + wsum[2] + wsum[3] + wsum[4];
        snorm = 10.f / fmaxf(sqrtf(tot), 1e-12f);
    }
    __syncthreads();
    if (t < DIM) {
        float v = sd * snorm;
        sess_i[b*DIM + t] = v;
        __bf16 h = (__bf16)v;
        Aq[(size_t)(12800 + b)*KPAD + t] = *(ushort_t*)&h;
    }
}

// convert rows of E (via optional index) into row-major bf16 [*, 320]
__global__ void conv_rows(const float* __restrict__ E, const int* __restrict__ idx,
                          ushort_t* __restrict__ dst, int row0, int nrows, int nvalid,
                          int plus1) {
    int t = threadIdx.x;                 // 320
    int r = blockIdx.x * 4 + t / 80;
    int c4 = (t % 80) * 4;
    if (r >= nrows) return;
    ushort4 u = make_ushort4(0, 0, 0, 0);
    if (r < nvalid && c4 < DIM) {
        int e = idx ? idx[r] : (r + plus1);
        float4 v = *(const float4*)(E + (size_t)e*DIM + c4);
        __bf16 a = (__bf16)v.x, b = (__bf16)v.y, c = (__bf16)v.z, d = (__bf16)v.w;
        u = make_ushort4(*(ushort_t*)&a, *(ushort_t*)&b, *(ushort_t*)&c, *(ushort_t*)&d);
    }
    *(ushort4*)(dst + (size_t)(row0 + r)*KPAD + c4) = u;
}

// Bmt[n][k] = map_dense[k][n] in bf16, zero-padded to [384][320]
__global__ void bmt_fill(const float* __restrict__ m, ushort_t* __restrict__ Bmt) {
    int n = blockIdx.x, k = threadIdx.x; // 384 x 320
    float v = (n < DIM && k < DIM) ? m[k*DIM + n] : 0.f;
    __bf16 h = (__bf16)v;
    Bmt[(size_t)n*KPAD + k] = *(ushort_t*)&h;
}

__global__ void inv_norm_k(const float* __restrict__ E, float* __restrict__ invn) {
    int n = blockIdx.x;
    const float* row = E + (long long)(n + 1)*DIM;
    int t = threadIdx.x;                 // 64
    float ss = 0.f;
    for (int k = t; k < DIM; k += 64) { float v = row[k]; ss += v*v; }
    for (int off = 32; off; off >>= 1) ss += __shfl_down(ss, off);
    if (t == 0) invn[n] = 1.f / fmaxf(sqrtf(ss), 1e-12f);
}

// ---------------- bf16 MFMA GEMM ----------------
// C[m][n] = sum_k A[m][k]*B[n][k], A/B row-major bf16 with stride KPAD=320.
// 128x128 block tile, 4 waves (2x2 of 64x64), 16x16x32 MFMA, BK=64,
// LDS in chunk-plane layout: [8 planes][128 rows][8 bf16] per operand.

__device__ __forceinline__ void glds16(const void* g, void* l) {
    __builtin_amdgcn_global_load_lds(
        (const __attribute__((address_space(1))) unsigned*)g,
        (__attribute__((address_space(3))) unsigned*)l, 16, 0, 0);
}

__device__ __forceinline__ void store_out(float* p, float v) { *p = v; }
__device__ __forceinline__ void store_out(ushort_t* p, float v) {
    __bf16 h = (__bf16)v;
    *p = *(ushort_t*)&h;
}

template <typename OUT>
__launch_bounds__(256)
__global__ void gemm_mfma(const ushort_t* __restrict__ A, int a_row0,
                          const ushort_t* __restrict__ B,
                          OUT* __restrict__ C, long long ldc, int c_row0) {
    __shared__ ushort_t As[8*128*8];
    __shared__ ushort_t Bs[8*128*8];
    const int t = threadIdx.x;
    const int wid = t >> 6, lane = t & 63;
    const int wm = wid >> 1, wn = wid & 1;
    const int q16 = lane >> 4, l16 = lane & 15;
    const int m0 = a_row0 + blockIdx.y * 128;
    const int n0 = blockIdx.x * 128;

    f32x4 acc[4][4];
#pragma unroll
    for (int i = 0; i < 4; ++i)
#pragma unroll
        for (int j = 0; j < 4; ++j)
#pragma unroll
            for (int r = 0; r < 4; ++r) acc[i][j][r] = 0.f;

    for (int kt = 0; kt < 5; ++kt) {
        const int kbase = kt * 64;
#pragma unroll
        for (int qq = 0; qq < 4; ++qq) {
            int idx = wid * 4 + qq;          // 0..15
            int p = idx >> 1, h = (idx & 1) * 64;
            glds16(A + (size_t)(m0 + h + lane)*KPAD + kbase + p*8, &As[(p*128 + h)*8]);
            glds16(B + (size_t)(n0 + h + lane)*KPAD + kbase + p*8, &Bs[(p*128 + h)*8]);
        }
        __syncthreads();
#pragma unroll
        for (int kk = 0; kk < 2; ++kk) {
            const int pl = kk * 4 + q16;
            bf16x8 af[4], bfr[4];
#pragma unroll
            for (int i = 0; i < 4; ++i)
                af[i] = *(const bf16x8*)&As[(pl*128 + wm*64 + i*16 + l16)*8];
#pragma unroll
            for (int j = 0; j < 4; ++j)
                bfr[j] = *(const bf16x8*)&Bs[(pl*128 + wn*64 + j*16 + l16)*8];
#pragma unroll
            for (int i = 0; i < 4; ++i)
#pragma unroll
                for (int j = 0; j < 4; ++j)
                    acc[i][j] = __builtin_amdgcn_mfma_f32_16x16x32_bf16(
                        af[i], bfr[j], acc[i][j], 0, 0, 0);
        }
        __syncthreads();
    }
    const long long rbase = (long long)(m0 - c_row0) + wm*64 + q16*4;
    const int cbase = n0 + wn*64 + l16;
#pragma unroll
    for (int i = 0; i < 4; ++i)
#pragma unroll
        for (int j = 0; j < 4; ++j) {
            int col = cbase + j*16;
#pragma unroll
            for (int r = 0; r < 4; ++r)
                store_out(C + (rbase + i*16 + r)*ldc + col, acc[i][j][r]);
        }
}

// ---------------- fused top-K on bf16 sims ----------------
__launch_bounds__(256)
__global__ void topk_k(const ushort_t* __restrict__ sim, int chunk_row0,
                       const float* __restrict__ E, const int* __restrict__ viewed,
                       const int* __restrict__ bought, int* __restrict__ topk) {
    const int r = chunk_row0 + blockIdx.x;
    const ushort_t* row = sim + (size_t)blockIdx.x * NPAD;
    const int t = threadIdx.x;           // 256

    __shared__ unsigned hist[4096];
    __shared__ unsigned partial[256];
    __shared__ unsigned s_T, s_total, s_above, s_cnt;
    __shared__ int      cidx[CAP];
    __shared__ double   cval[CAP];
    __shared__ float    qs[DIM];

    int qidx = (r < 6400) ? viewed[r] : bought[r - 6400];
    for (int k = t; k < DIM; k += 256) qs[k] = E[(size_t)qidx*DIM + k];

    for (int i = t; i < 4096; i += 256) hist[i] = 0;
    if (t == 0) s_cnt = 0;
    __syncthreads();

    for (int n = t; n < NITEMS; n += 256) {
        unsigned b = row[n];
        unsigned u = (b & 0x8000u) ? (~b & 0xFFFFu) : (b | 0x8000u);
        atomicAdd(&hist[u >> 4], 1u);
    }
    __syncthreads();
    { unsigned s = 0;
      for (int i = 0; i < 16; ++i) s += hist[t*16 + i];
      partial[t] = s; }
    __syncthreads();
    if (t == 0) {
        unsigned cum = 0; int c;
        for (c = 255; c > 0; --c) {
            if (cum + partial[c] >= TGT) break;
            cum += partial[c];
        }
        int bb;
        for (bb = c*16 + 15; bb > c*16; --bb) {
            if (cum + hist[bb] >= TGT) break;
            cum += hist[bb];
        }
        s_T = (unsigned)bb << 4;
        s_above = cum;
        s_total = cum + hist[bb];
    }
    __syncthreads();
    unsigned T = s_T;
    if (s_total > CAP) {
        // rare: refine on low 4 bits of the key inside the threshold bucket
        __syncthreads();
        if (t < 16) hist[t] = 0;
        __syncthreads();
        for (int n = t; n < NITEMS; n += 256) {
            unsigned b = row[n];
            unsigned u = (b & 0x8000u) ? (~b & 0xFFFFu) : (b | 0x8000u);
            if ((u >> 4) == (T >> 4)) atomicAdd(&hist[u & 15u], 1u);
        }
        __syncthreads();
        if (t == 0) {
            unsigned cum = s_above; int bb;
            for (bb = 15; bb > 0; --bb) {
                if (cum + hist[bb] >= TGT) break;
                cum += hist[bb];
            }
            s_T = T | (unsigned)bb;
            s_total = cum + hist[bb];
        }
        __syncthreads();
        T = s_T;
    }
    __syncthreads();

    for (int n = t; n < NITEMS; n += 256) {
        unsigned b = row[n];
        unsigned u = (b & 0x8000u) ? (~b & 0xFFFFu) : (b | 0x8000u);
        if (u >= T) {
            unsigned p = atomicAdd(&s_cnt, 1u);
            if (p < CAP) cidx[p] = n;
        }
    }
    __syncthreads();
    const int cnt = (int)min(s_cnt, (unsigned)CAP);

    // exact f64 re-rank, wave-cooperative (coalesced item-row reads)
    const int wid = t >> 6, lane = t & 63;
    for (int c = wid; c < cnt; c += 4) {
        int n = cidx[c];
        const float* irow = E + (size_t)(n + 1)*DIM;
        double acc = 0.0;
        for (int k = lane; k < DIM; k += 64)
            acc = fma((double)qs[k], (double)irow[k], acc);
        for (int off = 32; off; off >>= 1) acc += __shfl_down(acc, off);
        if (lane == 0) cval[c] = acc;
    }
    __syncthreads();
    const int SORT = (cnt <= 256) ? 256 : 512;
    for (int c = cnt + t; c < SORT; c += 256) { cval[c] = -1e300; cidx[c] = 0x7FFFFFFF; }
    __syncthreads();

    for (int k = 2; k <= SORT; k <<= 1) {
        for (int j = k >> 1; j > 0; j >>= 1) {
            if (t < (SORT >> 1)) {
                int i = ((t & ~(j - 1)) << 1) | (t & (j - 1));
                int p = i | j;
                bool up = (i & k) != 0;
                double v1 = cval[i], v2 = cval[p];
                int    i1 = cidx[i], i2 = cidx[p];
                bool less = (v1 < v2) || (v1 == v2 && i1 > i2);
                if (less != up) { cval[i] = v2; cval[p] = v1; cidx[i] = i2; cidx[p] = i1; }
            }
            __syncthreads();
        }
    }
    if (t < 100) topk[(size_t)r*100 + t] = cidx[t];
}

// ---------------- scores epilogue + loss ----------------
__global__ void scores_k(const float* __restrict__ sess_sim, const float* __restrict__ invn,
                         float* __restrict__ out, float* __restrict__ blse) {
    int b = blockIdx.x, t = threadIdx.x;   // 256
    const float* row = sess_sim + (size_t)b * NPAD;
    float mx = -1e30f;
    for (int n = t; n < NITEMS; n += 256) {
        float s = row[n] * invn[n];
        out[O_SCORES + (long long)b*NITEMS + n] = s;
        mx = fmaxf(mx, s);
    }
    for (int off = 32; off; off >>= 1) mx = fmaxf(mx, __shfl_down(mx, off));
    __shared__ float wred[4];
    __shared__ float smax;
    if ((t & 63) == 0) wred[t >> 6] = mx;
    __syncthreads();
    if (t == 0) smax = fmaxf(fmaxf(wred[0], wred[1]), fmaxf(wred[2], wred[3]));
    __syncthreads();
    float se = 0.f;
    for (int n = t; n < NITEMS; n += 256) {
        float s = out[O_SCORES + (long long)b*NITEMS + n];
        se += expf(s - smax);
    }
    for (int off = 32; off; off >>= 1) se += __shfl_down(se, off);
    if ((t & 63) == 0) wred[t >> 6] = se;
    __syncthreads();
    if (t == 0) blse[b] = smax + logf(wred[0] + wred[1] + wred[2] + wred[3]);
}

__global__ void loss_k(const float* __restrict__ out_scores, const int* __restrict__ targets,
                       const float* __restrict__ blse, float* __restrict__ out) {
    int t = threadIdx.x;                 // 64
    int lab = targets[t] - 1;
    float lp = out_scores[O_SCORES + (long long)t*NITEMS + lab] - blse[t];
    for (int off = 32; off; off >>= 1) lp += __shfl_down(lp, off);
    if (t == 0) out[0] = -lp / 64.f;
}

// ---------------- final gathers ----------------
__global__ void gather_k(const int* __restrict__ topk, const int* __restrict__ slices,
                         const float* __restrict__ all_mapped, float* __restrict__ out) {
    int r = blockIdx.x;                  // 0..12799
    int t = threadIdx.x;                 // 320
    if (t >= DIM) return;
    int rr = (r < 6400) ? r : r - 6400;
    long long obase = (r < 6400) ? O_SUB : O_COMP;
    int s  = rr % SNEG;
    int bl = rr / SNEG;
    long long outrow = (long long)bl*100 + s*NEXP;
    for (int e = 0; e < NEXP; ++e) {
        int sl = slices[e];
        int idx = topk[(size_t)r*100 + sl];
        out[obase + (outrow + e)*DIM + t] = all_mapped[(size_t)idx*MAPPAD + t];
    }
}

__global__ void smap_copy(const float* __restrict__ smbuf, float* __restrict__ out) {
    int b = blockIdx.x, t = threadIdx.x;
    if (t < DIM) out[O_SMAP + (long long)b*DIM + t] = smbuf[(size_t)b*MAPPAD + t];
}

// ---------------- host ----------------
extern "C" void kernel_launch(void* const* d_in, const int* in_sizes, int n_in,
                              void* d_out, int out_size, void* d_ws, size_t ws_size,
                              hipStream_t stream) {
    (void)in_sizes; (void)n_in; (void)out_size;
    const float* E     = (const float*)d_in[0];
    const float* pos   = (const float*)d_in[1];
    const float* w1    = (const float*)d_in[2];
    const float* w2    = (const float*)d_in[3];
    const float* g1w   = (const float*)d_in[4];
    const float* g1b   = (const float*)d_in[5];
    const float* g2w   = (const float*)d_in[6];
    const float* mapd  = (const float*)d_in[7];
    const int* inputs  = (const int*)d_in[8];
    const int* targets = (const int*)d_in[9];
    const int* masks   = (const int*)d_in[10];
    const int* viewed  = (const int*)d_in[11];
    const int* bought  = (const int*)d_in[12];
    const int* slices  = (const int*)d_in[13];
    float* out = (float*)d_out;

    char* w = (char*)d_ws;
    auto alloc = [&](size_t nbytes) {
        char* p = w;
        w += (nbytes + 255) & ~(size_t)255;
        return p;
    };
    float*    interfeat  = (float*)alloc(384000 * 4);
    float*    nh1        = (float*)alloc(384000 * 4);
    float*    hs         = (float*)alloc(19200 * 4);
    float*    posw1      = (float*)alloc(6000 * 4);
    float*    hsg        = (float*)alloc(19200 * 4);
    float*    betav      = (float*)alloc(1280 * 4);
    float*    sess_i     = (float*)alloc(19200 * 4);
    float*    invn       = (float*)alloc(39999 * 4);
    float*    blse       = (float*)alloc(64 * 4);
    int*      topk       = (int*)  alloc((size_t)12800 * 100 * 4);
    ushort_t* Aq         = (ushort_t*)alloc((size_t)NROWQ * KPAD * 2);
    ushort_t* Bi         = (ushort_t*)alloc((size_t)NPAD * KPAD * 2);
    ushort_t* Bmt        = (ushort_t*)alloc((size_t)MAPPAD * KPAD * 2);
    float*    all_mapped = (float*)alloc((size_t)NPAD * MAPPAD * 4);
    float*    sess_sim   = (float*)alloc((size_t)128 * NPAD * 4);
    float*    smbuf      = (float*)alloc((size_t)128 * MAPPAD * 4);
    ushort_t* simbf      = (ushort_t*)w;
    size_t rem = ws_size - (size_t)(w - (char*)d_ws);
    int CH = (int)(rem / ((size_t)NPAD * 2));
    CH = (CH / 128) * 128;
    if (CH > 1024) CH = 1024;
    if (CH < 128)  CH = 128;

    hipMemsetAsync(Aq, 0, (size_t)NROWQ * KPAD * 2, stream);

    // session-attention chain
    kA  <<<BATCH, 320, 0, stream>>>(E, inputs, masks, interfeat, hs);
    kB0 <<<LSEQ, 320, 0, stream>>>(pos, w1, posw1);
    kB0b<<<BATCH, 320, 0, stream>>>(hs, g2w, hsg);
    kB1 <<<BATCH*LSEQ, 320, 0, stream>>>(interfeat, w1, posw1, nh1);
    kB2 <<<BATCH*LSEQ, 320, 0, stream>>>(nh1, g1w, g1b, hsg, w2, masks, betav);
    kB3 <<<BATCH, 320, 0, stream>>>(interfeat, betav, sess_i, Aq);

    // bf16 operand builds
    conv_rows<<<(NPAD + 3)/4, 320, 0, stream>>>(E, nullptr, Bi, 0, NPAD, NITEMS, 1);
    conv_rows<<<1600, 320, 0, stream>>>(E, viewed, Aq, 0,    6400, 6400, 0);
    conv_rows<<<1600, 320, 0, stream>>>(E, bought, Aq, 6400, 6400, 6400, 0);
    bmt_fill<<<MAPPAD, 320, 0, stream>>>(mapd, Bmt);
    inv_norm_k<<<NITEMS, 64, 0, stream>>>(E, invn);

    // all_mapped = all_item @ map_dense  (f32 out)
    { dim3 g(MAPPAD/128, NPAD/128);
      gemm_mfma<float><<<g, 256, 0, stream>>>(Bi, 0, Bmt, all_mapped, MAPPAD, 0); }
    // sess_mapped
    { dim3 g(MAPPAD/128, 1);
      gemm_mfma<float><<<g, 256, 0, stream>>>(Aq, 12800, Bmt, smbuf, MAPPAD, 12800); }
    smap_copy<<<BATCH, 320, 0, stream>>>(smbuf, out);

    // sess scores (f32 out) + loss
    { dim3 g(NPAD/128, 1);
      gemm_mfma<float><<<g, 256, 0, stream>>>(Aq, 12800, Bi, sess_sim, NPAD, 12800); }
    scores_k<<<BATCH, 256, 0, stream>>>(sess_sim, invn, out, blse);
    loss_k<<<1, 64, 0, stream>>>(out, targets, blse, out);

    // big sim GEMM (bf16 out) in chunks + fused top-k
    for (int r0 = 0; r0 < 12800; r0 += CH) {
        int ch = (12800 - r0 < CH) ? (12800 - r0) : CH;
        dim3 g(NPAD/128, ch/128);
        gemm_mfma<ushort_t><<<g, 256, 0, stream>>>(Aq, r0, Bi, simbf, NPAD, r0);
        topk_k<<<ch, 256, 0, stream>>>(simbf, r0, E, viewed, bought, topk);
    }

    gather_k<<<12800, 320, 0, stream>>>(topk, slices, all_mapped, out);
}